// Round 8
// baseline (309.076 us; speedup 1.0000x reference)
//
#include <hip/hip_runtime.h>

typedef unsigned short ushort_t;
typedef unsigned long long u64_t;
typedef __attribute__((ext_vector_type(8))) short short8;
typedef __attribute__((ext_vector_type(4))) float float4v;

__device__ inline float b2f(ushort_t u) {
    unsigned x = ((unsigned)u) << 16;
    return __builtin_bit_cast(float, x);
}
__device__ inline ushort_t f2b(float f) {
    unsigned x = __builtin_bit_cast(unsigned, f);
    unsigned r = (x + 0x7fffu + ((x >> 16) & 1u)) >> 16;
    return (ushort_t)r;
}

// Wave-uniform int64-vs-int32 edge_index detection: load the int2 pair at
// edge slot e (valid bytes in BOTH layouts); int64-little-endian => odd word
// is always 0. Any nonzero odd word in the wave => int32.
// Returns src/dst for this edge.
__device__ inline void load_edge(const int* __restrict__ ei, int e, int E,
                                 int& s, int& d) {
    int ec = min(e, E - 1);
    int2 c64 = ((const int2*)ei)[ec];
    unsigned long long m = __ballot(c64.y != 0);
    if (m != 0ull) {  // int32 layout
        s = ei[ec];
        d = ei[(size_t)E + ec];
    } else {          // int64 layout
        s = c64.x;
        d = ((const int2*)ei)[(size_t)E + ec].x;
    }
}

// ---------------- mega kernel: count (atomic CSR degree+rank) + casts ----------------
// packed[d]: high 32 = edge count, low 32 = sum(w) in 8.24 fixed point.
// Returned old high word = within-segment rank. Grid sections:
// [0,gE): count | [gE,gE+gX): x->bf16 cast | [gE+gX, +256): W1/W2 cast.

__global__ __launch_bounds__(256) void k_mega(const int* __restrict__ ei,
                                              const float* __restrict__ w,
                                              const float* __restrict__ x,
                                              const float* __restrict__ W1,
                                              const float* __restrict__ W2,
                                              u64_t* packed, int* __restrict__ rank,
                                              ushort_t* __restrict__ xb,
                                              ushort_t* __restrict__ W1b,
                                              ushort_t* __restrict__ W2b,
                                              int E, int Nn, int gE, int gX) {
    int b = blockIdx.x;
    if (b < gE) {
        int e = b * 256 + threadIdx.x;
        int s, d;
        load_edge(ei, e, E, s, d);
        if (e < E) {
            if ((unsigned)s < (unsigned)Nn && (unsigned)d < (unsigned)Nn) {
                unsigned fx = (unsigned)(w[e] * 16777216.0f + 0.5f);
                u64_t old = atomicAdd(packed + d, (1ull << 32) | (u64_t)fx);
                rank[e] = (int)(old >> 32);
            } else {
                rank[e] = -1;
            }
        }
    } else if (b < gE + gX) {
        int i = (b - gE) * 256 + threadIdx.x;  // float4 index
        if (i < Nn * 32) {
            float4v v = ((const float4v*)x)[i];
            ushort4 o;
            o.x = f2b(v[0]); o.y = f2b(v[1]); o.z = f2b(v[2]); o.w = f2b(v[3]);
            ((ushort4*)xb)[i] = o;
        }
    } else {
        int i = (b - gE - gX) * 256 + threadIdx.x;
        if (i < 32768) W1b[i] = f2b(W1[i]);
        else if (i < 65536) W2b[i - 32768] = f2b(W2[i - 32768]);
    }
}

__device__ inline int cnt_hi(const u64_t* packed, int i) {
    return ((const int*)packed)[2 * i + 1];  // little-endian high word
}

// ---------------- 3-phase multi-block exclusive scan over cnt_hi ----------------

__global__ __launch_bounds__(256) void k_scan_a(const u64_t* __restrict__ packed,
                                                int* __restrict__ bsum, int Nn) {
    int b = blockIdx.x, t = threadIdx.x;
    int base = b * 2048 + t * 8;
    int s = 0;
#pragma unroll
    for (int j = 0; j < 8; ++j) { int i = base + j; if (i < Nn) s += cnt_hi(packed, i); }
#pragma unroll
    for (int off = 1; off < 64; off <<= 1) s += __shfl_xor(s, off);
    __shared__ int wsum[4];
    if ((t & 63) == 0) wsum[t >> 6] = s;
    __syncthreads();
    if (t == 0) bsum[b] = wsum[0] + wsum[1] + wsum[2] + wsum[3];
}

// nb <= 64. One wave.
__global__ void k_scan_b(const int* __restrict__ bsum, int* __restrict__ bbase,
                         int nb, int* __restrict__ offs, int Nn) {
    int t = threadIdx.x;
    int own = (t < nb) ? bsum[t] : 0;
    int v = own;
#pragma unroll
    for (int off = 1; off < 64; off <<= 1) {
        int u = __shfl_up(v, off);
        if (t >= off) v += u;
    }
    if (t < nb) bbase[t] = v - own;  // exclusive
    if (t == 63) offs[Nn] = v;       // grand total
}

// scan_c + dinv fused (both read packed[])
__global__ __launch_bounds__(256) void k_scan_c(const u64_t* __restrict__ packed,
                                                const int* __restrict__ bbase,
                                                int* __restrict__ offs,
                                                float* __restrict__ dinv, int Nn) {
    int b = blockIdx.x, t = threadIdx.x;
    int base = b * 2048 + t * 8;
    u64_t pk[8];
    int v[8];
    int s = 0;
#pragma unroll
    for (int j = 0; j < 8; ++j) {
        int i = base + j;
        pk[j] = (i < Nn) ? packed[i] : 0ull;
        v[j] = (int)(pk[j] >> 32);
        s += v[j];
    }
    __shared__ int sd[256];
    sd[t] = s;
    __syncthreads();
    for (int off = 1; off < 256; off <<= 1) {
        int u = (t >= off) ? sd[t - off] : 0;
        __syncthreads();
        sd[t] += u;
        __syncthreads();
    }
    int pos = bbase[b] + sd[t] - s;
#pragma unroll
    for (int j = 0; j < 8; ++j) {
        int i = base + j;
        if (i < Nn) {
            offs[i] = pos; pos += v[j];
            float deg = 1.0f + (float)(unsigned)(pk[j] & 0xFFFFFFFFull) * (1.0f / 16777216.0f);
            dinv[i] = rsqrtf(deg);  // deg >= 1 (self loop)
        }
    }
}

// ---------------- scatter (atomic-free): edata[pos] = {src, bits(norm)} ----------------

__global__ void k_scatter(const int* __restrict__ ei, const float* __restrict__ w,
                          const float* __restrict__ dinv,
                          const int* __restrict__ offs,
                          const int* __restrict__ rank,
                          int2* __restrict__ edata, int E, int Nn) {
    int e = blockIdx.x * 256 + threadIdx.x;
    int s, d;
    load_edge(ei, e, E, s, d);  // full wave participates in ballot
    if (e >= E) return;
    int r = rank[e];
    if (r < 0) return;
    int pos = offs[d] + r;
    float nw = dinv[s] * w[e] * dinv[d];
    int2 p;
    p.x = s;
    p.y = __builtin_bit_cast(int, nw);
    edata[pos] = p;
}

// ---------------- split-wave gather core ----------------
// Half p = lane>>5 handles edges i+p, i+p+2, ... Each lane loads ushort4
// (8 B): 32 lanes cover a 256 B row; one VMEM instruction fetches two rows.
// Tail clamps to e-1 (duplicate line, free) with norm zeroed.

__device__ inline void agg_edges(const ushort_t* __restrict__ src,
                                 const int2* __restrict__ edata,
                                 int s, int e, int hl, int p, float* a) {
    int i = s;
    for (; i + 7 < e; i += 8) {
#pragma unroll
        for (int j = 0; j < 4; ++j) {
            int idx = i + p + 2 * j;
            int2 ed = edata[idx];
            float nw = __builtin_bit_cast(float, ed.y);
            ushort4 q = ((const ushort4*)(src + (size_t)ed.x * 128))[hl];
            a[0] += b2f(q.x) * nw; a[1] += b2f(q.y) * nw;
            a[2] += b2f(q.z) * nw; a[3] += b2f(q.w) * nw;
        }
    }
    for (; i < e; i += 2) {
        int idx = i + p;
        int ic = min(idx, e - 1);
        int2 ed = edata[ic];
        float nw = (idx < e) ? __builtin_bit_cast(float, ed.y) : 0.f;
        ushort4 q = ((const ushort4*)(src + (size_t)ed.x * 128))[hl];
        a[0] += b2f(q.x) * nw; a[1] += b2f(q.y) * nw;
        a[2] += b2f(q.z) * nw; a[3] += b2f(q.w) * nw;
    }
}

// ---------------- fused agg1 + GEMM: h2 = relu((A@x) @ W1^T + b1) @ W2^T ----------------
// Block = 64 nodes. Phase 0: wave w aggregates nodes [w*16,w*16+16) (split-wave
// gather, 8 rows in flight) into LDS axl. Phase 1: wave w computes 64 rows x
// cols [w*64,w*64+64) with W1 slice prefetched, A-frags from axl. ReLU'd
// 64x256 tile -> LDS. Phase 2: wave w computes cols [w*32,w*32+32) from tile
// + prefetched W2 slice. MFMA 16x16x32 bf16: A row=lane&15,k=quad*8+j;
// B col=lane&15,k=quad*8+j; D col=lane&15,row=quad*4+reg.

__global__ __launch_bounds__(256, 2) void k_gemm_fused(const ushort_t* __restrict__ xb,
                                                       const int* __restrict__ offs,
                                                       const int2* __restrict__ edata,
                                                       const float* __restrict__ dinv,
                                                       const ushort_t* __restrict__ W1b,
                                                       const float* __restrict__ b1v,
                                                       const ushort_t* __restrict__ W2b,
                                                       ushort_t* __restrict__ h2, int Nn) {
    __shared__ ushort_t axl[64][136];   // 17408 B, row stride 272 B (16B-aligned)
    __shared__ ushort_t tile[64][264];  // 33792 B
    int tid = threadIdx.x, wid = tid >> 6, lane = tid & 63;
    int hl = lane & 31, p = lane >> 5;
    int blk = blockIdx.x * 64;

    // ---- phase 0: aggregate 16 nodes per wave into axl ----
    for (int n = 0; n < 16; ++n) {
        int v = blk + wid * 16 + n;
        float a[4] = {0.f, 0.f, 0.f, 0.f};
        int s = 0, e = 0;
        if (v < Nn) {
            s = offs[v]; e = offs[v + 1];
            if (p == 0) {  // self-loop, half 0 only
                float dv = dinv[v];
                float sn = dv * dv;
                ushort4 pq = ((const ushort4*)(xb + (size_t)v * 128))[hl];
                a[0] = b2f(pq.x) * sn; a[1] = b2f(pq.y) * sn;
                a[2] = b2f(pq.z) * sn; a[3] = b2f(pq.w) * sn;
            }
        }
        agg_edges(xb, edata, s, e, hl, p, a);
#pragma unroll
        for (int j = 0; j < 4; ++j) a[j] += __shfl_xor(a[j], 32);
        if (p == 0) {
            ushort4 o;
            o.x = f2b(a[0]); o.y = f2b(a[1]); o.z = f2b(a[2]); o.w = f2b(a[3]);
            *(ushort4*)&axl[wid * 16 + n][hl * 4] = o;
        }
    }
    __syncthreads();

    // ---- phase 1: GEMM1 from axl ----
    int m = lane & 15, q = lane >> 4;
    short8 wf[4][4];  // [nt][kt]
#pragma unroll
    for (int nt = 0; nt < 4; ++nt) {
        const ushort_t* wb = W1b + (size_t)(wid * 64 + nt * 16 + m) * 128 + q * 8;
#pragma unroll
        for (int kt = 0; kt < 4; ++kt) wf[nt][kt] = *(const short8*)(wb + kt * 32);
    }

    float4v acc1[4][4];  // [mi][nt]
#pragma unroll
    for (int mi = 0; mi < 4; ++mi)
#pragma unroll
        for (int nt = 0; nt < 4; ++nt) acc1[mi][nt] = (float4v){0.f, 0.f, 0.f, 0.f};

#pragma unroll
    for (int kt = 0; kt < 4; ++kt)
#pragma unroll
        for (int mi = 0; mi < 4; ++mi) {
            short8 af = *(const short8*)&axl[mi * 16 + m][kt * 32 + q * 8];
#pragma unroll
            for (int nt = 0; nt < 4; ++nt)
                acc1[mi][nt] = __builtin_amdgcn_mfma_f32_16x16x32_bf16(
                    af, wf[nt][kt], acc1[mi][nt], 0, 0, 0);
        }

#pragma unroll
    for (int nt = 0; nt < 4; ++nt) {
        int col = wid * 64 + nt * 16 + m;
        float bb = b1v[col];
#pragma unroll
        for (int mi = 0; mi < 4; ++mi) {
#pragma unroll
            for (int r = 0; r < 4; ++r) {
                float v = acc1[mi][nt][r] + bb;
                v = v > 0.f ? v : 0.f;
                tile[mi * 16 + q * 4 + r][col] = f2b(v);
            }
        }
    }
    __syncthreads();

    // ---- phase 2: GEMM2 from tile ----
    short8 w2f[2][8];  // [n2][kt]
#pragma unroll
    for (int n2 = 0; n2 < 2; ++n2) {
        const ushort_t* wb = W2b + (size_t)(wid * 32 + n2 * 16 + m) * 256 + q * 8;
#pragma unroll
        for (int kt = 0; kt < 8; ++kt) w2f[n2][kt] = *(const short8*)(wb + kt * 32);
    }

    float4v acc2[4][2];  // [mi][n2]
#pragma unroll
    for (int mi = 0; mi < 4; ++mi)
#pragma unroll
        for (int n2 = 0; n2 < 2; ++n2) acc2[mi][n2] = (float4v){0.f, 0.f, 0.f, 0.f};

#pragma unroll
    for (int kt = 0; kt < 8; ++kt) {
#pragma unroll
        for (int mi = 0; mi < 4; ++mi) {
            short8 a2 = *(const short8*)&tile[mi * 16 + m][kt * 32 + q * 8];
#pragma unroll
            for (int n2 = 0; n2 < 2; ++n2)
                acc2[mi][n2] = __builtin_amdgcn_mfma_f32_16x16x32_bf16(
                    a2, w2f[n2][kt], acc2[mi][n2], 0, 0, 0);
        }
    }

#pragma unroll
    for (int mi = 0; mi < 4; ++mi) {
#pragma unroll
        for (int n2 = 0; n2 < 2; ++n2) {
            int col = wid * 32 + n2 * 16 + m;
#pragma unroll
            for (int r = 0; r < 4; ++r) {
                int row = blk + mi * 16 + q * 4 + r;
                if (row < Nn) h2[(size_t)row * 128 + col] = f2b(acc2[mi][n2][r]);
            }
        }
    }
}

// ---------------- aggregation 2 + bias + LayerNorm (fp32 out) ----------------

__global__ __launch_bounds__(256) void k_agg2_ln(const ushort_t* __restrict__ h2,
                                                 const int* __restrict__ offs,
                                                 const int2* __restrict__ edata,
                                                 const float* __restrict__ dinv,
                                                 const float* __restrict__ b2v,
                                                 const float* __restrict__ gv,
                                                 const float* __restrict__ bev,
                                                 float* __restrict__ out, int Nn) {
    int v = (blockIdx.x * blockDim.x + threadIdx.x) >> 6;
    int lane = threadIdx.x & 63;
    if (v >= Nn) return;
    int hl = lane & 31, p = lane >> 5;
    float a[4] = {0.f, 0.f, 0.f, 0.f};
    if (p == 0) {
        float dv = dinv[v];
        float sn = dv * dv;
        ushort4 pq = ((const ushort4*)(h2 + (size_t)v * 128))[hl];
        a[0] = b2f(pq.x) * sn; a[1] = b2f(pq.y) * sn;
        a[2] = b2f(pq.z) * sn; a[3] = b2f(pq.w) * sn;
    }
    int s = offs[v], e = offs[v + 1];
    agg_edges(h2, edata, s, e, hl, p, a);
#pragma unroll
    for (int j = 0; j < 4; ++j) a[j] += __shfl_xor(a[j], 32);

    int d0 = hl * 4;
#pragma unroll
    for (int j = 0; j < 4; ++j) a[j] += b2v[d0 + j];

    // every dim held twice (both halves) -> divide by 256
    float ssum = a[0] + a[1] + a[2] + a[3];
    float ssq = a[0] * a[0] + a[1] * a[1] + a[2] * a[2] + a[3] * a[3];
#pragma unroll
    for (int off = 1; off < 64; off <<= 1) {
        ssum += __shfl_xor(ssum, off);
        ssq += __shfl_xor(ssq, off);
    }
    float mu = ssum * (1.0f / 256.0f);
    float var = ssq * (1.0f / 256.0f) - mu * mu;
    float r = rsqrtf(var + 1e-5f);
    if (p == 0) {
        float4v o;
#pragma unroll
        for (int j = 0; j < 4; ++j)
            o[j] = (a[j] - mu) * r * gv[d0 + j] + bev[d0 + j];
        ((float4v*)(out + (size_t)v * 128))[hl] = o;
    }
}

// ---------------- launch ----------------

extern "C" void kernel_launch(void* const* d_in, const int* in_sizes, int n_in,
                              void* d_out, int out_size, void* d_ws, size_t ws_size,
                              hipStream_t stream) {
    const float* x   = (const float*)d_in[0];  // [N,128] f32
    const int*   ei  = (const int*)d_in[1];    // [2,E] int32/int64 (detected)
    const float* ew  = (const float*)d_in[2];  // [E] f32
    const float* W1  = (const float*)d_in[3];  // [256,128] f32
    const float* b1v = (const float*)d_in[4];  // [256]
    const float* W2  = (const float*)d_in[5];  // [128,256]
    const float* b2v = (const float*)d_in[6];  // [128]
    const float* gv  = (const float*)d_in[7];  // [128]
    const float* bev = (const float*)d_in[8];  // [128]
    float* out = (float*)d_out;

    const int Nn = in_sizes[0] / 128;
    const int E  = in_sizes[2];

    char* base = (char*)d_ws;
    size_t off = 0;
    auto alloc = [&](size_t bytes) {
        char* p = base + off;
        off = (off + bytes + 255) & ~(size_t)255;
        return p;
    };
    u64_t*  packed = (u64_t*)alloc((size_t)Nn * 8);
    float*  dinv   = (float*)alloc((size_t)Nn * 4);
    int*    offs   = (int*)alloc((size_t)(Nn + 1) * 4);
    int*    bsum   = (int*)alloc(64 * 4);
    int*    bbase  = (int*)alloc(64 * 4);
    int*    rank   = (int*)alloc((size_t)E * 4);
    int2*   edata  = (int2*)alloc((size_t)E * 8);
    ushort_t* xb   = (ushort_t*)alloc((size_t)Nn * 128 * 2);
    ushort_t* h2   = (ushort_t*)alloc((size_t)Nn * 128 * 2);
    ushort_t* W1b  = (ushort_t*)alloc(32768 * 2);
    ushort_t* W2b  = (ushort_t*)alloc(32768 * 2);
    (void)ws_size; (void)n_in; (void)out_size;

    int gE = (E + 255) / 256;
    int gX = (Nn * 32 + 255) / 256;   // float4 count / 256
    int gW = (Nn + 3) / 4;            // wave per node
    int gG = (Nn + 63) / 64;          // 64 rows per block
    int nb = (Nn + 2047) / 2048;      // scan blocks (<= 64)

    hipMemsetAsync(packed, 0, (size_t)Nn * 8, stream);
    k_mega<<<gE + gX + 256, 256, 0, stream>>>(ei, ew, x, W1, W2, packed, rank,
                                              xb, W1b, W2b, E, Nn, gE, gX);
    k_scan_a<<<nb, 256, 0, stream>>>(packed, bsum, Nn);
    k_scan_b<<<1, 64, 0, stream>>>(bsum, bbase, nb, offs, Nn);
    k_scan_c<<<nb, 256, 0, stream>>>(packed, bbase, offs, dinv, Nn);
    k_scatter<<<gE, 256, 0, stream>>>(ei, ew, dinv, offs, rank, edata, E, Nn);
    k_gemm_fused<<<gG, 256, 0, stream>>>(xb, offs, edata, dinv, W1b, b1v, W2b, h2, Nn);
    k_agg2_ln<<<gW, 256, 0, stream>>>(h2, offs, edata, dinv, b2v, gv, bev, out, Nn);
}

// Round 9
// 261.635 us; speedup vs baseline: 1.1813x; 1.1813x over previous
//
#include <hip/hip_runtime.h>

typedef unsigned short ushort_t;
typedef unsigned long long u64_t;
typedef __attribute__((ext_vector_type(8))) short short8;
typedef __attribute__((ext_vector_type(4))) float float4v;

__device__ inline float b2f(ushort_t u) {
    unsigned x = ((unsigned)u) << 16;
    return __builtin_bit_cast(float, x);
}
__device__ inline ushort_t f2b(float f) {
    unsigned x = __builtin_bit_cast(unsigned, f);
    unsigned r = (x + 0x7fffu + ((x >> 16) & 1u)) >> 16;
    return (ushort_t)r;
}

// Wave-uniform int64-vs-int32 edge_index detection: load the int2 pair at
// edge slot e (valid bytes in BOTH layouts); int64-little-endian => odd word
// is always 0. Any nonzero odd word in the wave => int32.
__device__ inline void load_edge(const int* __restrict__ ei, int e, int E,
                                 int& s, int& d) {
    int ec = min(e, E - 1);
    int2 c64 = ((const int2*)ei)[ec];
    unsigned long long m = __ballot(c64.y != 0);
    if (m != 0ull) {  // int32 layout
        s = ei[ec];
        d = ei[(size_t)E + ec];
    } else {          // int64 layout
        s = c64.x;
        d = ((const int2*)ei)[(size_t)E + ec].x;
    }
}

// ---------------- mega kernel: count (atomic CSR degree+rank) + casts ----------------
// packed[d]: high 32 = edge count, low 32 = sum(w) in 8.24 fixed point.
// Returned old high word = within-segment rank. Grid sections:
// [0,gE): count | [gE,gE+gX): x->bf16 cast | [gE+gX, +256): W1/W2 cast.

__global__ __launch_bounds__(256) void k_mega(const int* __restrict__ ei,
                                              const float* __restrict__ w,
                                              const float* __restrict__ x,
                                              const float* __restrict__ W1,
                                              const float* __restrict__ W2,
                                              u64_t* packed, int* __restrict__ rank,
                                              ushort_t* __restrict__ xb,
                                              ushort_t* __restrict__ W1b,
                                              ushort_t* __restrict__ W2b,
                                              int E, int Nn, int gE, int gX) {
    int b = blockIdx.x;
    if (b < gE) {
        int e = b * 256 + threadIdx.x;
        int s, d;
        load_edge(ei, e, E, s, d);
        if (e < E) {
            if ((unsigned)s < (unsigned)Nn && (unsigned)d < (unsigned)Nn) {
                unsigned fx = (unsigned)(w[e] * 16777216.0f + 0.5f);
                u64_t old = atomicAdd(packed + d, (1ull << 32) | (u64_t)fx);
                rank[e] = (int)(old >> 32);
            } else {
                rank[e] = -1;
            }
        }
    } else if (b < gE + gX) {
        int i = (b - gE) * 256 + threadIdx.x;  // float4 index
        if (i < Nn * 32) {
            float4v v = ((const float4v*)x)[i];
            ushort4 o;
            o.x = f2b(v[0]); o.y = f2b(v[1]); o.z = f2b(v[2]); o.w = f2b(v[3]);
            ((ushort4*)xb)[i] = o;
        }
    } else {
        int i = (b - gE - gX) * 256 + threadIdx.x;
        if (i < 32768) W1b[i] = f2b(W1[i]);
        else if (i < 65536) W2b[i - 32768] = f2b(W2[i - 32768]);
    }
}

__device__ inline int cnt_hi(const u64_t* packed, int i) {
    return ((const int*)packed)[2 * i + 1];  // little-endian high word
}

// ---------------- 3-phase multi-block exclusive scan over cnt_hi ----------------

__global__ __launch_bounds__(256) void k_scan_a(const u64_t* __restrict__ packed,
                                                int* __restrict__ bsum, int Nn) {
    int b = blockIdx.x, t = threadIdx.x;
    int base = b * 2048 + t * 8;
    int s = 0;
#pragma unroll
    for (int j = 0; j < 8; ++j) { int i = base + j; if (i < Nn) s += cnt_hi(packed, i); }
#pragma unroll
    for (int off = 1; off < 64; off <<= 1) s += __shfl_xor(s, off);
    __shared__ int wsum[4];
    if ((t & 63) == 0) wsum[t >> 6] = s;
    __syncthreads();
    if (t == 0) bsum[b] = wsum[0] + wsum[1] + wsum[2] + wsum[3];
}

// nb <= 64. One wave.
__global__ void k_scan_b(const int* __restrict__ bsum, int* __restrict__ bbase,
                         int nb, int* __restrict__ offs, int Nn) {
    int t = threadIdx.x;
    int own = (t < nb) ? bsum[t] : 0;
    int v = own;
#pragma unroll
    for (int off = 1; off < 64; off <<= 1) {
        int u = __shfl_up(v, off);
        if (t >= off) v += u;
    }
    if (t < nb) bbase[t] = v - own;  // exclusive
    if (t == 63) offs[Nn] = v;       // grand total
}

// scan_c + dinv fused (both read packed[])
__global__ __launch_bounds__(256) void k_scan_c(const u64_t* __restrict__ packed,
                                                const int* __restrict__ bbase,
                                                int* __restrict__ offs,
                                                float* __restrict__ dinv, int Nn) {
    int b = blockIdx.x, t = threadIdx.x;
    int base = b * 2048 + t * 8;
    u64_t pk[8];
    int v[8];
    int s = 0;
#pragma unroll
    for (int j = 0; j < 8; ++j) {
        int i = base + j;
        pk[j] = (i < Nn) ? packed[i] : 0ull;
        v[j] = (int)(pk[j] >> 32);
        s += v[j];
    }
    __shared__ int sd[256];
    sd[t] = s;
    __syncthreads();
    for (int off = 1; off < 256; off <<= 1) {
        int u = (t >= off) ? sd[t - off] : 0;
        __syncthreads();
        sd[t] += u;
        __syncthreads();
    }
    int pos = bbase[b] + sd[t] - s;
#pragma unroll
    for (int j = 0; j < 8; ++j) {
        int i = base + j;
        if (i < Nn) {
            offs[i] = pos; pos += v[j];
            float deg = 1.0f + (float)(unsigned)(pk[j] & 0xFFFFFFFFull) * (1.0f / 16777216.0f);
            dinv[i] = rsqrtf(deg);  // deg >= 1 (self loop)
        }
    }
}

// ---------------- scatter (atomic-free): edata[pos] = {src, bits(norm)} ----------------

__global__ void k_scatter(const int* __restrict__ ei, const float* __restrict__ w,
                          const float* __restrict__ dinv,
                          const int* __restrict__ offs,
                          const int* __restrict__ rank,
                          int2* __restrict__ edata, int E, int Nn) {
    int e = blockIdx.x * 256 + threadIdx.x;
    int s, d;
    load_edge(ei, e, E, s, d);  // full wave participates in ballot
    if (e >= E) return;
    int r = rank[e];
    if (r < 0) return;
    int pos = offs[d] + r;
    float nw = dinv[s] * w[e] * dinv[d];
    int2 p;
    p.x = s;
    p.y = __builtin_bit_cast(int, nw);
    edata[pos] = p;
}

// ---------------- split-wave gather core ----------------
// Half p = lane>>5 handles edges i+p, i+p+2, ... Each lane loads ushort4
// (8 B): 32 lanes cover a 256 B row; one VMEM instruction fetches two rows.
// Tail clamps to e-1 (duplicate line, free) with norm zeroed.

__device__ inline void agg_edges(const ushort_t* __restrict__ src,
                                 const int2* __restrict__ edata,
                                 int s, int e, int hl, int p, float* a) {
    int i = s;
    for (; i + 7 < e; i += 8) {
#pragma unroll
        for (int j = 0; j < 4; ++j) {
            int idx = i + p + 2 * j;
            int2 ed = edata[idx];
            float nw = __builtin_bit_cast(float, ed.y);
            ushort4 q = ((const ushort4*)(src + (size_t)ed.x * 128))[hl];
            a[0] += b2f(q.x) * nw; a[1] += b2f(q.y) * nw;
            a[2] += b2f(q.z) * nw; a[3] += b2f(q.w) * nw;
        }
    }
    for (; i < e; i += 2) {
        int idx = i + p;
        int ic = min(idx, e - 1);
        int2 ed = edata[ic];
        float nw = (idx < e) ? __builtin_bit_cast(float, ed.y) : 0.f;
        ushort4 q = ((const ushort4*)(src + (size_t)ed.x * 128))[hl];
        a[0] += b2f(q.x) * nw; a[1] += b2f(q.y) * nw;
        a[2] += b2f(q.z) * nw; a[3] += b2f(q.w) * nw;
    }
}

// aggregation 1: ax = A_norm @ x  (bf16 in/out, fp32 acc), wave per node
__global__ __launch_bounds__(256) void k_agg1(const ushort_t* __restrict__ xb,
                                              const int* __restrict__ offs,
                                              const int2* __restrict__ edata,
                                              const float* __restrict__ dinv,
                                              ushort_t* __restrict__ ax, int Nn) {
    int v = (blockIdx.x * blockDim.x + threadIdx.x) >> 6;
    int lane = threadIdx.x & 63;
    if (v >= Nn) return;
    int hl = lane & 31, p = lane >> 5;
    float a[4] = {0.f, 0.f, 0.f, 0.f};
    if (p == 0) {  // self-loop in half 0 only
        float dv = dinv[v];
        float sn = dv * dv;
        ushort4 pq = ((const ushort4*)(xb + (size_t)v * 128))[hl];
        a[0] = b2f(pq.x) * sn; a[1] = b2f(pq.y) * sn;
        a[2] = b2f(pq.z) * sn; a[3] = b2f(pq.w) * sn;
    }
    int s = offs[v], e = offs[v + 1];
    agg_edges(xb, edata, s, e, hl, p, a);
#pragma unroll
    for (int j = 0; j < 4; ++j) a[j] += __shfl_xor(a[j], 32);
    if (p == 0) {
        ushort4 o;
        o.x = f2b(a[0]); o.y = f2b(a[1]); o.z = f2b(a[2]); o.w = f2b(a[3]);
        ((ushort4*)(ax + (size_t)v * 128))[hl] = o;
    }
}

// ---------------- fused GEMM: h2 = relu(ax @ W1^T + b1) @ W2^T ----------------
// Block = 64 rows, 4 waves split the N dimension (no redundant W loads).
// Phase 1: wave w computes 64 rows x cols [w*64,w*64+64): W1 slice + a-frags
// fully prefetched into registers. ReLU'd 64x256 bf16 tile -> shared LDS.
// Phase 2: wave w computes 64 rows x cols [w*32,w*32+32) from LDS A-frags
// and prefetched W2 slice. MFMA 16x16x32 bf16 layouts: A row=lane&15,
// k=quad*8+j; B col=lane&15, k=quad*8+j; D col=lane&15, row=quad*4+reg.

__global__ __launch_bounds__(256, 2) void k_gemm_fused(const ushort_t* __restrict__ ax,
                                                       const ushort_t* __restrict__ W1b,
                                                       const float* __restrict__ b1v,
                                                       const ushort_t* __restrict__ W2b,
                                                       ushort_t* __restrict__ h2, int Nn) {
    __shared__ ushort_t tile[64][264];  // 33792 B; stride 264: 16B-aligned rows
    int tid = threadIdx.x, wid = tid >> 6, lane = tid & 63;
    int m = lane & 15, q = lane >> 4;
    int blk = blockIdx.x * 64;

    short8 wf[4][4];  // [nt][kt]
#pragma unroll
    for (int nt = 0; nt < 4; ++nt) {
        const ushort_t* wb = W1b + (size_t)(wid * 64 + nt * 16 + m) * 128 + q * 8;
#pragma unroll
        for (int kt = 0; kt < 4; ++kt) wf[nt][kt] = *(const short8*)(wb + kt * 32);
    }
    short8 af[4][4];  // [mi][kt]
#pragma unroll
    for (int mi = 0; mi < 4; ++mi) {
        int arow = blk + mi * 16 + m;
        bool rv = arow < Nn;
        const ushort_t* ab = ax + (size_t)arow * 128 + q * 8;
#pragma unroll
        for (int kt = 0; kt < 4; ++kt)
            af[mi][kt] = rv ? *(const short8*)(ab + kt * 32) : (short8)0;
    }

    float4v acc1[4][4];  // [mi][nt]
#pragma unroll
    for (int mi = 0; mi < 4; ++mi)
#pragma unroll
        for (int nt = 0; nt < 4; ++nt) acc1[mi][nt] = (float4v){0.f, 0.f, 0.f, 0.f};

#pragma unroll
    for (int kt = 0; kt < 4; ++kt)
#pragma unroll
        for (int mi = 0; mi < 4; ++mi)
#pragma unroll
            for (int nt = 0; nt < 4; ++nt)
                acc1[mi][nt] = __builtin_amdgcn_mfma_f32_16x16x32_bf16(
                    af[mi][kt], wf[nt][kt], acc1[mi][nt], 0, 0, 0);

#pragma unroll
    for (int nt = 0; nt < 4; ++nt) {
        int col = wid * 64 + nt * 16 + m;
        float bb = b1v[col];
#pragma unroll
        for (int mi = 0; mi < 4; ++mi) {
#pragma unroll
            for (int r = 0; r < 4; ++r) {
                float v = acc1[mi][nt][r] + bb;
                v = v > 0.f ? v : 0.f;
                tile[mi * 16 + q * 4 + r][col] = f2b(v);
            }
        }
    }
    __syncthreads();

    short8 w2f[2][8];  // [n2][kt]
#pragma unroll
    for (int n2 = 0; n2 < 2; ++n2) {
        const ushort_t* wb = W2b + (size_t)(wid * 32 + n2 * 16 + m) * 256 + q * 8;
#pragma unroll
        for (int kt = 0; kt < 8; ++kt) w2f[n2][kt] = *(const short8*)(wb + kt * 32);
    }

    float4v acc2[4][2];  // [mi][n2]
#pragma unroll
    for (int mi = 0; mi < 4; ++mi)
#pragma unroll
        for (int n2 = 0; n2 < 2; ++n2) acc2[mi][n2] = (float4v){0.f, 0.f, 0.f, 0.f};

#pragma unroll
    for (int kt = 0; kt < 8; ++kt) {
#pragma unroll
        for (int mi = 0; mi < 4; ++mi) {
            short8 a2 = *(const short8*)&tile[mi * 16 + m][kt * 32 + q * 8];
#pragma unroll
            for (int n2 = 0; n2 < 2; ++n2)
                acc2[mi][n2] = __builtin_amdgcn_mfma_f32_16x16x32_bf16(
                    a2, w2f[n2][kt], acc2[mi][n2], 0, 0, 0);
        }
    }

#pragma unroll
    for (int mi = 0; mi < 4; ++mi) {
#pragma unroll
        for (int n2 = 0; n2 < 2; ++n2) {
            int col = wid * 32 + n2 * 16 + m;
#pragma unroll
            for (int r = 0; r < 4; ++r) {
                int row = blk + mi * 16 + q * 4 + r;
                if (row < Nn) h2[(size_t)row * 128 + col] = f2b(acc2[mi][n2][r]);
            }
        }
    }
}

// ---------------- aggregation 2 + bias + LayerNorm (fp32 out) ----------------

__global__ __launch_bounds__(256) void k_agg2_ln(const ushort_t* __restrict__ h2,
                                                 const int* __restrict__ offs,
                                                 const int2* __restrict__ edata,
                                                 const float* __restrict__ dinv,
                                                 const float* __restrict__ b2v,
                                                 const float* __restrict__ gv,
                                                 const float* __restrict__ bev,
                                                 float* __restrict__ out, int Nn) {
    int v = (blockIdx.x * blockDim.x + threadIdx.x) >> 6;
    int lane = threadIdx.x & 63;
    if (v >= Nn) return;
    int hl = lane & 31, p = lane >> 5;
    float a[4] = {0.f, 0.f, 0.f, 0.f};
    if (p == 0) {
        float dv = dinv[v];
        float sn = dv * dv;
        ushort4 pq = ((const ushort4*)(h2 + (size_t)v * 128))[hl];
        a[0] = b2f(pq.x) * sn; a[1] = b2f(pq.y) * sn;
        a[2] = b2f(pq.z) * sn; a[3] = b2f(pq.w) * sn;
    }
    int s = offs[v], e = offs[v + 1];
    agg_edges(h2, edata, s, e, hl, p, a);
#pragma unroll
    for (int j = 0; j < 4; ++j) a[j] += __shfl_xor(a[j], 32);

    int d0 = hl * 4;
#pragma unroll
    for (int j = 0; j < 4; ++j) a[j] += b2v[d0 + j];

    // every dim held twice (both halves) -> divide by 256
    float ssum = a[0] + a[1] + a[2] + a[3];
    float ssq = a[0] * a[0] + a[1] * a[1] + a[2] * a[2] + a[3] * a[3];
#pragma unroll
    for (int off = 1; off < 64; off <<= 1) {
        ssum += __shfl_xor(ssum, off);
        ssq += __shfl_xor(ssq, off);
    }
    float mu = ssum * (1.0f / 256.0f);
    float var = ssq * (1.0f / 256.0f) - mu * mu;
    float r = rsqrtf(var + 1e-5f);
    if (p == 0) {
        float4v o;
#pragma unroll
        for (int j = 0; j < 4; ++j)
            o[j] = (a[j] - mu) * r * gv[d0 + j] + bev[d0 + j];
        ((float4v*)(out + (size_t)v * 128))[hl] = o;
    }
}

// ---------------- launch ----------------

extern "C" void kernel_launch(void* const* d_in, const int* in_sizes, int n_in,
                              void* d_out, int out_size, void* d_ws, size_t ws_size,
                              hipStream_t stream) {
    const float* x   = (const float*)d_in[0];  // [N,128] f32
    const int*   ei  = (const int*)d_in[1];    // [2,E] int32/int64 (detected)
    const float* ew  = (const float*)d_in[2];  // [E] f32
    const float* W1  = (const float*)d_in[3];  // [256,128] f32
    const float* b1v = (const float*)d_in[4];  // [256]
    const float* W2  = (const float*)d_in[5];  // [128,256]
    const float* b2v = (const float*)d_in[6];  // [128]
    const float* gv  = (const float*)d_in[7];  // [128]
    const float* bev = (const float*)d_in[8];  // [128]
    float* out = (float*)d_out;

    const int Nn = in_sizes[0] / 128;
    const int E  = in_sizes[2];

    char* base = (char*)d_ws;
    size_t off = 0;
    auto alloc = [&](size_t bytes) {
        char* p = base + off;
        off = (off + bytes + 255) & ~(size_t)255;
        return p;
    };
    u64_t*  packed = (u64_t*)alloc((size_t)Nn * 8);
    float*  dinv   = (float*)alloc((size_t)Nn * 4);
    int*    offs   = (int*)alloc((size_t)(Nn + 1) * 4);
    int*    bsum   = (int*)alloc(64 * 4);
    int*    bbase  = (int*)alloc(64 * 4);
    int*    rank   = (int*)alloc((size_t)E * 4);
    int2*   edata  = (int2*)alloc((size_t)E * 8);
    ushort_t* xb   = (ushort_t*)alloc((size_t)Nn * 128 * 2);
    ushort_t* h2   = (ushort_t*)alloc((size_t)Nn * 128 * 2);
    ushort_t* W1b  = (ushort_t*)alloc(32768 * 2);
    ushort_t* W2b  = (ushort_t*)alloc(32768 * 2);
    ushort_t* ax   = (ushort_t*)d_out;  // stage ax in d_out (bf16); dead before final write
    (void)ws_size; (void)n_in; (void)out_size;

    int gE = (E + 255) / 256;
    int gX = (Nn * 32 + 255) / 256;   // float4 count / 256
    int gW = (Nn + 3) / 4;            // wave per node
    int gG = (Nn + 63) / 64;          // 64 rows per block
    int nb = (Nn + 2047) / 2048;      // scan blocks (<= 64)

    hipMemsetAsync(packed, 0, (size_t)Nn * 8, stream);
    k_mega<<<gE + gX + 256, 256, 0, stream>>>(ei, ew, x, W1, W2, packed, rank,
                                              xb, W1b, W2b, E, Nn, gE, gX);
    k_scan_a<<<nb, 256, 0, stream>>>(packed, bsum, Nn);
    k_scan_b<<<1, 64, 0, stream>>>(bsum, bbase, nb, offs, Nn);
    k_scan_c<<<nb, 256, 0, stream>>>(packed, bbase, offs, dinv, Nn);
    k_scatter<<<gE, 256, 0, stream>>>(ei, ew, dinv, offs, rank, edata, E, Nn);
    k_agg1<<<gW, 256, 0, stream>>>(xb, offs, edata, dinv, ax, Nn);
    k_gemm_fused<<<gG, 256, 0, stream>>>(ax, W1b, b1v, W2b, h2, Nn);
    k_agg2_ln<<<gW, 256, 0, stream>>>(h2, offs, edata, dinv, b2v, gv, bev, out, Nn);
}